// Round 5
// baseline (437.641 us; speedup 1.0000x reference)
//
#include <hip/hip_runtime.h>
#include <hip/hip_bf16.h>

#define D 256

typedef __attribute__((ext_vector_type(8))) short short8;
typedef __attribute__((ext_vector_type(4))) short short4v;
typedef __attribute__((ext_vector_type(4))) float floatx4;
typedef __attribute__((ext_vector_type(4))) int intx4;

static __device__ __forceinline__ unsigned short f2bf(float f) {
  unsigned int u = __builtin_bit_cast(unsigned int, f);
  u += 0x7FFFu + ((u >> 16) & 1u);   // RNE to bf16
  return (unsigned short)(u >> 16);
}
static __device__ __forceinline__ float bf2f(unsigned short s) {
  unsigned int u = ((unsigned int)s) << 16;
  return __builtin_bit_cast(float, u);
}

// ---- detect int64 vs int32 edge_index storage (one wave) ---------------
__global__ void detect_kernel(const int* __restrict__ ei32, int* __restrict__ flag) {
  int lane = threadIdx.x;
  int v = ei32[2 * lane + 1];
  unsigned long long nz = __ballot(v != 0);
  if (lane == 0) *flag = (nz == 0ULL) ? 1 : 0;   // 1 => int64 layout
}

static __device__ __forceinline__ int edge_at(const void* ei, int is64, long long idx) {
  return is64 ? (int)((const long long*)ei)[idx] : ((const int*)ei)[idx];
}

// ---- CSR build ---------------------------------------------------------
__global__ void count_kernel(const void* __restrict__ ei, const int* __restrict__ flag,
                             int* __restrict__ counts, int E, int N) {
  int is64 = *flag;
  int e = blockIdx.x * blockDim.x + threadIdx.x;
  if (e < E) {
    int c = edge_at(ei, is64, (long long)E + e);
    if ((unsigned)c < (unsigned)N) atomicAdd(&counts[c], 1);
  }
}

// phase A: per-block (1024-elem chunk) reduce
__global__ __launch_bounds__(256) void scan_blocksum_kernel(const int* __restrict__ counts,
                                                            int* __restrict__ bsum, int n) {
  __shared__ int sh[256];
  int b = blockIdx.x, t = threadIdx.x;
  int base = b * 1024 + t * 4;
  int s = 0;
  if (base + 3 < n) {
    intx4 v = *(const intx4*)&counts[base];
    s = v[0] + v[1] + v[2] + v[3];
  } else {
    for (int j = 0; j < 4; ++j) if (base + j < n) s += counts[base + j];
  }
  sh[t] = s;
  __syncthreads();
  for (int d = 128; d > 0; d >>= 1) {
    if (t < d) sh[t] += sh[t + d];
    __syncthreads();
  }
  if (t == 0) bsum[b] = sh[0];
}

// phase B: scan the (small) block-sum array; out[i]=exclusive, out[n]=total
__global__ void scan_kernel(const int* __restrict__ counts, int* __restrict__ offsets, int n) {
  __shared__ int part[1024];
  int t = threadIdx.x;
  int CH = (n + 1023) / 1024;
  int lo = t * CH;
  int hi = lo + CH; if (hi > n) hi = n;
  int s = 0;
  for (int i = lo; i < hi; ++i) s += counts[i];
  part[t] = s;
  __syncthreads();
  for (int d = 1; d < 1024; d <<= 1) {
    int v = (t >= d) ? part[t - d] : 0;
    __syncthreads();
    part[t] += v;
    __syncthreads();
  }
  int run = (t == 0) ? 0 : part[t - 1];
  for (int i = lo; i < hi; ++i) { offsets[i] = run; run += counts[i]; }
  if (hi == n) offsets[n] = run;
}

// phase C: chunk-local exclusive scan + block offset
__global__ __launch_bounds__(256) void scan_apply_kernel(const int* __restrict__ counts,
                                                         const int* __restrict__ boff,
                                                         int* __restrict__ offsets, int n) {
  __shared__ int sh[256];
  int b = blockIdx.x, t = threadIdx.x;
  int base = b * 1024 + t * 4;
  int c0 = (base + 0 < n) ? counts[base + 0] : 0;
  int c1 = (base + 1 < n) ? counts[base + 1] : 0;
  int c2 = (base + 2 < n) ? counts[base + 2] : 0;
  int c3 = (base + 3 < n) ? counts[base + 3] : 0;
  sh[t] = c0 + c1 + c2 + c3;
  __syncthreads();
  for (int d = 1; d < 256; d <<= 1) {
    int v = (t >= d) ? sh[t - d] : 0;
    __syncthreads();
    sh[t] += v;
    __syncthreads();
  }
  int excl = (t == 0 ? 0 : sh[t - 1]) + boff[b];
  if (base + 0 < n) offsets[base + 0] = excl;
  if (base + 1 < n) offsets[base + 1] = excl + c0;
  if (base + 2 < n) offsets[base + 2] = excl + c0 + c1;
  if (base + 3 < n) offsets[base + 3] = excl + c0 + c1 + c2;
  if (b == (int)gridDim.x - 1 && t == 255) offsets[n] = boff[gridDim.x];
}

__global__ void fill_kernel(const void* __restrict__ ei, const int* __restrict__ flag,
                            const int* __restrict__ offsets, int* __restrict__ cursor,
                            int* __restrict__ edge_src, int E, int N) {
  int is64 = *flag;
  int e = blockIdx.x * blockDim.x + threadIdx.x;
  if (e < E) {
    int c = edge_at(ei, is64, (long long)E + e);
    int s = edge_at(ei, is64, (long long)e);
    if ((unsigned)c < (unsigned)N && (unsigned)s < (unsigned)N) {
      int pos = atomicAdd(&cursor[c], 1);
      edge_src[offsets[c] + pos] = s;
    }
  }
}

// ---- W transpose + bf16: Wt[oc][k] (k<256 -> W_l, else W_r) ------------
__global__ void wt_kernel(const float* __restrict__ Wl, const float* __restrict__ Wr,
                          unsigned short* __restrict__ Wt) {
  int idx = blockIdx.x * blockDim.x + threadIdx.x;
  int oc = idx >> 9, k = idx & 511;
  float v = (k < 256) ? Wl[k * 256 + oc] : Wr[(k - 256) * 256 + oc];
  Wt[idx] = f2bf(v);
}

// ---- x_src f32 -> bf16 (8 elems/thread) --------------------------------
__global__ void xcast_kernel(const float* __restrict__ x, unsigned short* __restrict__ xb,
                             long long n8) {
  long long i = (long long)blockIdx.x * blockDim.x + threadIdx.x;
  if (i >= n8) return;
  floatx4 f0 = *(const floatx4*)&x[i * 8];
  floatx4 f1 = *(const floatx4*)&x[i * 8 + 4];
  short8 v;
  v[0] = (short)f2bf(f0[0]); v[1] = (short)f2bf(f0[1]);
  v[2] = (short)f2bf(f0[2]); v[3] = (short)f2bf(f0[3]);
  v[4] = (short)f2bf(f1[0]); v[5] = (short)f2bf(f1[1]);
  v[6] = (short)f2bf(f1[2]); v[7] = (short)f2bf(f1[3]);
  *(short8*)&xb[i * 8] = v;
}

// ---- scatter-mean via CSR, bf16 in / bf16 out, 1 wave per node ---------
__global__ __launch_bounds__(64) void aggr_bf_kernel(const unsigned short* __restrict__ xsb,
                                                     const int* __restrict__ offsets,
                                                     const int* __restrict__ edge_src,
                                                     unsigned short* __restrict__ aggr) {
  int node = blockIdx.x;
  int t = threadIdx.x;                  // feature group: 4t..4t+3
  int start = offsets[node], end = offsets[node + 1];
  float a0 = 0.f, a1 = 0.f, a2 = 0.f, a3 = 0.f;
  int i = start;
  for (; i + 4 <= end; i += 4) {
    int s0 = edge_src[i], s1 = edge_src[i + 1], s2 = edge_src[i + 2], s3 = edge_src[i + 3];
    short4v v0 = *(const short4v*)&xsb[(size_t)s0 * D + t * 4];
    short4v v1 = *(const short4v*)&xsb[(size_t)s1 * D + t * 4];
    short4v v2 = *(const short4v*)&xsb[(size_t)s2 * D + t * 4];
    short4v v3 = *(const short4v*)&xsb[(size_t)s3 * D + t * 4];
    a0 += bf2f((unsigned short)v0[0]) + bf2f((unsigned short)v1[0]) + bf2f((unsigned short)v2[0]) + bf2f((unsigned short)v3[0]);
    a1 += bf2f((unsigned short)v0[1]) + bf2f((unsigned short)v1[1]) + bf2f((unsigned short)v2[1]) + bf2f((unsigned short)v3[1]);
    a2 += bf2f((unsigned short)v0[2]) + bf2f((unsigned short)v1[2]) + bf2f((unsigned short)v2[2]) + bf2f((unsigned short)v3[2]);
    a3 += bf2f((unsigned short)v0[3]) + bf2f((unsigned short)v1[3]) + bf2f((unsigned short)v2[3]) + bf2f((unsigned short)v3[3]);
  }
  for (; i < end; ++i) {
    short4v v = *(const short4v*)&xsb[(size_t)edge_src[i] * D + t * 4];
    a0 += bf2f((unsigned short)v[0]); a1 += bf2f((unsigned short)v[1]);
    a2 += bf2f((unsigned short)v[2]); a3 += bf2f((unsigned short)v[3]);
  }
  int deg = end - start;
  float inv = 1.f / (float)(deg > 0 ? deg : 1);
  short4v r;
  r[0] = (short)f2bf(a0 * inv); r[1] = (short)f2bf(a1 * inv);
  r[2] = (short)f2bf(a2 * inv); r[3] = (short)f2bf(a3 * inv);
  *(short4v*)&aggr[(size_t)node * D + t * 4] = r;
}

// ---- f32 fallback aggr (aggr lives in d_out) ----------------------------
__global__ void aggr_f32_kernel(const float* __restrict__ xsrc, const int* __restrict__ offsets,
                                const int* __restrict__ edge_src, float* __restrict__ aggr) {
  int node = blockIdx.x;
  int t = threadIdx.x;
  int start = offsets[node], end = offsets[node + 1];
  float acc = 0.f;
  int i = start;
  for (; i + 4 <= end; i += 4) {
    int s0 = edge_src[i], s1 = edge_src[i + 1], s2 = edge_src[i + 2], s3 = edge_src[i + 3];
    acc += xsrc[(size_t)s0 * D + t];
    acc += xsrc[(size_t)s1 * D + t];
    acc += xsrc[(size_t)s2 * D + t];
    acc += xsrc[(size_t)s3 * D + t];
  }
  for (; i < end; ++i) acc += xsrc[(size_t)edge_src[i] * D + t];
  int deg = end - start;
  aggr[(size_t)node * D + t] = acc / (float)(deg > 0 ? deg : 1);
}

// ---- fused GEMM v2: K split into 2 phases, 32 KB LDS -> 4-5 blocks/CU --
// A_lds[64][256] bf16; XOR-swizzled 16B chunks: chunk' = chunk ^ (row&7).
// phase 0: A = aggr rows (k=0..255, bf16); phase 1: A = x_tgt rows (f32->bf16).
template <bool AGGR_BF16>
__global__ __launch_bounds__(256) void gemm_kernel(const void* __restrict__ aggrp,
                                                   const float* __restrict__ xtgt,
                                                   const unsigned short* __restrict__ Wt,
                                                   const float* __restrict__ bias,
                                                   float* __restrict__ out, int n_tgt) {
  __shared__ __align__(16) unsigned short A_lds[64 * 256];   // 32 KB
  int t = threadIdx.x;
  int mbase = blockIdx.x * 64;
  int lane = t & 63, w = t >> 6;
  int lr = lane & 15, lq = lane >> 4;

  floatx4 acc[4][4];
#pragma unroll
  for (int mt = 0; mt < 4; ++mt)
#pragma unroll
    for (int nt = 0; nt < 4; ++nt) acc[mt][nt] = (floatx4){0.f, 0.f, 0.f, 0.f};

  const unsigned short* WtW = Wt + ((size_t)(64 * w + lr)) * 512 + lq * 8;

  // ---- phase 0: stage aggr ----
#pragma unroll
  for (int it = 0; it < 8; ++it) {
    int chunk = it * 256 + t;           // 0..2047
    int r = chunk >> 5, c = chunk & 31;
    int node = mbase + r;
    short8 v = {0, 0, 0, 0, 0, 0, 0, 0};
    if (node < n_tgt) {
      if (AGGR_BF16) {
        v = *(const short8*)&((const unsigned short*)aggrp)[(size_t)node * D + c * 8];
      } else {
        const float* ap = (const float*)aggrp;
        floatx4 f0 = *(const floatx4*)&ap[(size_t)node * D + c * 8];
        floatx4 f1 = *(const floatx4*)&ap[(size_t)node * D + c * 8 + 4];
        v[0] = (short)f2bf(f0[0]); v[1] = (short)f2bf(f0[1]);
        v[2] = (short)f2bf(f0[2]); v[3] = (short)f2bf(f0[3]);
        v[4] = (short)f2bf(f1[0]); v[5] = (short)f2bf(f1[1]);
        v[6] = (short)f2bf(f1[2]); v[7] = (short)f2bf(f1[3]);
      }
    }
    int sc = c ^ (r & 7);
    *(short8*)&A_lds[r * 256 + sc * 8] = v;
  }
  __syncthreads();
  // ---- compute phase 0 (k = 0..255) ----
#pragma unroll
  for (int ks = 0; ks < 8; ++ks) {
    short8 a[4], b[4];
#pragma unroll
    for (int mt = 0; mt < 4; ++mt) {
      int row = 16 * mt + lr;
      int chunk = (ks * 4 + lq) ^ (row & 7);
      a[mt] = *(const short8*)&A_lds[row * 256 + chunk * 8];
    }
#pragma unroll
    for (int nt = 0; nt < 4; ++nt)
      b[nt] = *(const short8*)&WtW[(size_t)nt * 16 * 512 + ks * 32];
#pragma unroll
    for (int mt = 0; mt < 4; ++mt)
#pragma unroll
      for (int nt = 0; nt < 4; ++nt)
        acc[mt][nt] = __builtin_amdgcn_mfma_f32_16x16x32_bf16(a[mt], b[nt], acc[mt][nt], 0, 0, 0);
  }
  __syncthreads();   // everyone done reading phase-0 A_lds

  // ---- phase 1: stage x_tgt (f32 -> bf16) ----
#pragma unroll
  for (int it = 0; it < 8; ++it) {
    int chunk = it * 256 + t;
    int r = chunk >> 5, c = chunk & 31;
    int node = mbase + r;
    floatx4 f0 = {0.f, 0.f, 0.f, 0.f}, f1 = {0.f, 0.f, 0.f, 0.f};
    if (node < n_tgt) {
      f0 = *(const floatx4*)&xtgt[(size_t)node * D + c * 8];
      f1 = *(const floatx4*)&xtgt[(size_t)node * D + c * 8 + 4];
    }
    short8 v;
    v[0] = (short)f2bf(f0[0]); v[1] = (short)f2bf(f0[1]);
    v[2] = (short)f2bf(f0[2]); v[3] = (short)f2bf(f0[3]);
    v[4] = (short)f2bf(f1[0]); v[5] = (short)f2bf(f1[1]);
    v[6] = (short)f2bf(f1[2]); v[7] = (short)f2bf(f1[3]);
    int sc = c ^ (r & 7);
    *(short8*)&A_lds[r * 256 + sc * 8] = v;
  }
  __syncthreads();
  // ---- compute phase 1 (k = 256..511) ----
#pragma unroll
  for (int ks = 0; ks < 8; ++ks) {
    short8 a[4], b[4];
#pragma unroll
    for (int mt = 0; mt < 4; ++mt) {
      int row = 16 * mt + lr;
      int chunk = (ks * 4 + lq) ^ (row & 7);
      a[mt] = *(const short8*)&A_lds[row * 256 + chunk * 8];
    }
#pragma unroll
    for (int nt = 0; nt < 4; ++nt)
      b[nt] = *(const short8*)&WtW[(size_t)nt * 16 * 512 + (8 + ks) * 32];
#pragma unroll
    for (int mt = 0; mt < 4; ++mt)
#pragma unroll
      for (int nt = 0; nt < 4; ++nt)
        acc[mt][nt] = __builtin_amdgcn_mfma_f32_16x16x32_bf16(a[mt], b[nt], acc[mt][nt], 0, 0, 0);
  }

  // epilogue: row=(lane>>4)*4+reg, col=lane&15
#pragma unroll
  for (int nt = 0; nt < 4; ++nt) {
    int oc = 64 * w + 16 * nt + lr;
    float bv = bias[oc];
#pragma unroll
    for (int mt = 0; mt < 4; ++mt) {
#pragma unroll
      for (int r4 = 0; r4 < 4; ++r4) {
        int node = mbase + 16 * mt + lq * 4 + r4;
        if (node < n_tgt) out[(size_t)node * D + oc] = acc[mt][nt][r4] + bv;
      }
    }
  }
}

extern "C" void kernel_launch(void* const* d_in, const int* in_sizes, int n_in,
                              void* d_out, int out_size, void* d_ws, size_t ws_size,
                              hipStream_t stream) {
  const float* x_src = (const float*)d_in[0];
  const float* x_tgt = (const float*)d_in[1];
  const void* ei = d_in[2];
  const float* W_l = (const float*)d_in[3];
  const float* b_l = (const float*)d_in[4];
  const float* W_r = (const float*)d_in[5];
  float* out = (float*)d_out;

  const int N_s = in_sizes[0] / D;     // source nodes
  const int N_t = in_sizes[1] / D;     // target nodes
  const int E = in_sizes[2] / 2;       // edges

  char* ws = (char*)d_ws;
  size_t o = 0;
  auto alloc = [&](size_t bytes) { size_t cur = o; o = (o + bytes + 255) & ~(size_t)255; return cur; };
  int* flag              = (int*)(ws + alloc(4));
  int* counts            = (int*)(ws + alloc((size_t)N_t * 4));
  int* offsets           = (int*)(ws + alloc(((size_t)N_t + 1) * 4));
  int* cursor            = (int*)(ws + alloc((size_t)N_t * 4));
  size_t zero_end        = o;
  int SB = (N_t + 1023) / 1024;
  int* bsum              = (int*)(ws + alloc(((size_t)SB) * 4));
  int* boff              = (int*)(ws + alloc(((size_t)SB + 1) * 4));
  int* edge_src          = (int*)(ws + alloc((size_t)E * 4));
  unsigned short* Wt     = (unsigned short*)(ws + alloc((size_t)256 * 512 * 2));
  size_t base_end        = o;
  unsigned short* xsrc_b = (unsigned short*)(ws + alloc((size_t)N_s * D * 2));
  unsigned short* aggr_b = (unsigned short*)(ws + alloc((size_t)N_t * D * 2));
  size_t bf16_end        = o;

  bool bf16_path = (ws_size >= bf16_end);
  (void)base_end;

  hipMemsetAsync(ws, 0, zero_end, stream);

  int eb = (E + 255) / 256;
  detect_kernel<<<1, 64, 0, stream>>>((const int*)ei, flag);
  count_kernel<<<eb, 256, 0, stream>>>(ei, flag, counts, E, N_t);
  scan_blocksum_kernel<<<SB, 256, 0, stream>>>(counts, bsum, N_t);
  scan_kernel<<<1, 1024, 0, stream>>>(bsum, boff, SB);
  scan_apply_kernel<<<SB, 256, 0, stream>>>(counts, boff, offsets, N_t);
  fill_kernel<<<eb, 256, 0, stream>>>(ei, flag, offsets, cursor, edge_src, E, N_t);
  wt_kernel<<<512, 256, 0, stream>>>(W_l, W_r, Wt);

  if (bf16_path) {
    long long n8 = (long long)N_s * D / 8;
    xcast_kernel<<<(int)((n8 + 255) / 256), 256, 0, stream>>>(x_src, xsrc_b, n8);
    aggr_bf_kernel<<<N_t, 64, 0, stream>>>(xsrc_b, offsets, edge_src, aggr_b);
    gemm_kernel<true><<<(N_t + 63) / 64, 256, 0, stream>>>(aggr_b, x_tgt, Wt, b_l, out, N_t);
  } else {
    aggr_f32_kernel<<<N_t, 256, 0, stream>>>(x_src, offsets, edge_src, out);
    gemm_kernel<false><<<(N_t + 63) / 64, 256, 0, stream>>>(out, x_tgt, Wt, b_l, out, N_t);
  }
}

// Round 6
// 389.763 us; speedup vs baseline: 1.1228x; 1.1228x over previous
//
#include <hip/hip_runtime.h>
#include <hip/hip_bf16.h>

#define D 256

typedef __attribute__((ext_vector_type(8))) short short8;
typedef __attribute__((ext_vector_type(4))) short short4v;
typedef __attribute__((ext_vector_type(4))) float floatx4;
typedef __attribute__((ext_vector_type(4))) int intx4;

static __device__ __forceinline__ unsigned short f2bf(float f) {
  unsigned int u = __builtin_bit_cast(unsigned int, f);
  u += 0x7FFFu + ((u >> 16) & 1u);   // RNE to bf16
  return (unsigned short)(u >> 16);
}
static __device__ __forceinline__ float bf2f(unsigned short s) {
  unsigned int u = ((unsigned int)s) << 16;
  return __builtin_bit_cast(float, u);
}

static __device__ __forceinline__ void gld_lds16(const unsigned short* g, unsigned short* l) {
  __builtin_amdgcn_global_load_lds(
      (const __attribute__((address_space(1))) unsigned int*)g,
      (__attribute__((address_space(3))) unsigned int*)l, 16, 0, 0);
}

// ---- detect int64 vs int32 edge_index storage (one wave) ---------------
__global__ void detect_kernel(const int* __restrict__ ei32, int* __restrict__ flag) {
  int lane = threadIdx.x;
  int v = ei32[2 * lane + 1];
  unsigned long long nz = __ballot(v != 0);
  if (lane == 0) *flag = (nz == 0ULL) ? 1 : 0;   // 1 => int64 layout
}

static __device__ __forceinline__ int edge_at(const void* ei, int is64, long long idx) {
  return is64 ? (int)((const long long*)ei)[idx] : ((const int*)ei)[idx];
}

// ---- CSR build ---------------------------------------------------------
__global__ void count_kernel(const void* __restrict__ ei, const int* __restrict__ flag,
                             int* __restrict__ counts, int E, int N) {
  int is64 = *flag;
  int e = blockIdx.x * blockDim.x + threadIdx.x;
  if (e < E) {
    int c = edge_at(ei, is64, (long long)E + e);
    if ((unsigned)c < (unsigned)N) atomicAdd(&counts[c], 1);
  }
}

__global__ __launch_bounds__(256) void scan_blocksum_kernel(const int* __restrict__ counts,
                                                            int* __restrict__ bsum, int n) {
  __shared__ int sh[256];
  int b = blockIdx.x, t = threadIdx.x;
  int base = b * 1024 + t * 4;
  int s = 0;
  if (base + 3 < n) {
    intx4 v = *(const intx4*)&counts[base];
    s = v[0] + v[1] + v[2] + v[3];
  } else {
    for (int j = 0; j < 4; ++j) if (base + j < n) s += counts[base + j];
  }
  sh[t] = s;
  __syncthreads();
  for (int d = 128; d > 0; d >>= 1) {
    if (t < d) sh[t] += sh[t + d];
    __syncthreads();
  }
  if (t == 0) bsum[b] = sh[0];
}

__global__ void scan_kernel(const int* __restrict__ counts, int* __restrict__ offsets, int n) {
  __shared__ int part[1024];
  int t = threadIdx.x;
  int CH = (n + 1023) / 1024;
  int lo = t * CH;
  int hi = lo + CH; if (hi > n) hi = n;
  int s = 0;
  for (int i = lo; i < hi; ++i) s += counts[i];
  part[t] = s;
  __syncthreads();
  for (int d = 1; d < 1024; d <<= 1) {
    int v = (t >= d) ? part[t - d] : 0;
    __syncthreads();
    part[t] += v;
    __syncthreads();
  }
  int run = (t == 0) ? 0 : part[t - 1];
  for (int i = lo; i < hi; ++i) { offsets[i] = run; run += counts[i]; }
  if (hi == n) offsets[n] = run;
}

__global__ __launch_bounds__(256) void scan_apply_kernel(const int* __restrict__ counts,
                                                         const int* __restrict__ boff,
                                                         int* __restrict__ offsets, int n) {
  __shared__ int sh[256];
  int b = blockIdx.x, t = threadIdx.x;
  int base = b * 1024 + t * 4;
  int c0 = (base + 0 < n) ? counts[base + 0] : 0;
  int c1 = (base + 1 < n) ? counts[base + 1] : 0;
  int c2 = (base + 2 < n) ? counts[base + 2] : 0;
  int c3 = (base + 3 < n) ? counts[base + 3] : 0;
  sh[t] = c0 + c1 + c2 + c3;
  __syncthreads();
  for (int d = 1; d < 256; d <<= 1) {
    int v = (t >= d) ? sh[t - d] : 0;
    __syncthreads();
    sh[t] += v;
    __syncthreads();
  }
  int excl = (t == 0 ? 0 : sh[t - 1]) + boff[b];
  if (base + 0 < n) offsets[base + 0] = excl;
  if (base + 1 < n) offsets[base + 1] = excl + c0;
  if (base + 2 < n) offsets[base + 2] = excl + c0 + c1;
  if (base + 3 < n) offsets[base + 3] = excl + c0 + c1 + c2;
  if (b == (int)gridDim.x - 1 && t == 255) offsets[n] = boff[gridDim.x];
}

__global__ void fill_kernel(const void* __restrict__ ei, const int* __restrict__ flag,
                            const int* __restrict__ offsets, int* __restrict__ cursor,
                            int* __restrict__ edge_src, int E, int N) {
  int is64 = *flag;
  int e = blockIdx.x * blockDim.x + threadIdx.x;
  if (e < E) {
    int c = edge_at(ei, is64, (long long)E + e);
    int s = edge_at(ei, is64, (long long)e);
    if ((unsigned)c < (unsigned)N && (unsigned)s < (unsigned)N) {
      int pos = atomicAdd(&cursor[c], 1);
      edge_src[offsets[c] + pos] = s;
    }
  }
}

// ---- W transpose + bf16: Wt[oc][k] (k<256 -> W_l, else W_r) ------------
__global__ void wt_kernel(const float* __restrict__ Wl, const float* __restrict__ Wr,
                          unsigned short* __restrict__ Wt) {
  int idx = blockIdx.x * blockDim.x + threadIdx.x;
  int oc = idx >> 9, k = idx & 511;
  float v = (k < 256) ? Wl[k * 256 + oc] : Wr[(k - 256) * 256 + oc];
  Wt[idx] = f2bf(v);
}

// ---- x_src f32 -> bf16 (8 elems/thread) --------------------------------
__global__ void xcast_kernel(const float* __restrict__ x, unsigned short* __restrict__ xb,
                             long long n8) {
  long long i = (long long)blockIdx.x * blockDim.x + threadIdx.x;
  if (i >= n8) return;
  floatx4 f0 = *(const floatx4*)&x[i * 8];
  floatx4 f1 = *(const floatx4*)&x[i * 8 + 4];
  short8 v;
  v[0] = (short)f2bf(f0[0]); v[1] = (short)f2bf(f0[1]);
  v[2] = (short)f2bf(f0[2]); v[3] = (short)f2bf(f0[3]);
  v[4] = (short)f2bf(f1[0]); v[5] = (short)f2bf(f1[1]);
  v[6] = (short)f2bf(f1[2]); v[7] = (short)f2bf(f1[3]);
  *(short8*)&xb[i * 8] = v;
}

// ---- scatter-mean via CSR, bf16 in / bf16 out, 1 wave per node ---------
__global__ __launch_bounds__(64) void aggr_bf_kernel(const unsigned short* __restrict__ xsb,
                                                     const int* __restrict__ offsets,
                                                     const int* __restrict__ edge_src,
                                                     unsigned short* __restrict__ aggr) {
  int node = blockIdx.x;
  int t = threadIdx.x;                  // feature group: 4t..4t+3
  int start = offsets[node], end = offsets[node + 1];
  float a0 = 0.f, a1 = 0.f, a2 = 0.f, a3 = 0.f;
  int i = start;
  for (; i + 4 <= end; i += 4) {
    int s0 = edge_src[i], s1 = edge_src[i + 1], s2 = edge_src[i + 2], s3 = edge_src[i + 3];
    short4v v0 = *(const short4v*)&xsb[(size_t)s0 * D + t * 4];
    short4v v1 = *(const short4v*)&xsb[(size_t)s1 * D + t * 4];
    short4v v2 = *(const short4v*)&xsb[(size_t)s2 * D + t * 4];
    short4v v3 = *(const short4v*)&xsb[(size_t)s3 * D + t * 4];
    a0 += bf2f((unsigned short)v0[0]) + bf2f((unsigned short)v1[0]) + bf2f((unsigned short)v2[0]) + bf2f((unsigned short)v3[0]);
    a1 += bf2f((unsigned short)v0[1]) + bf2f((unsigned short)v1[1]) + bf2f((unsigned short)v2[1]) + bf2f((unsigned short)v3[1]);
    a2 += bf2f((unsigned short)v0[2]) + bf2f((unsigned short)v1[2]) + bf2f((unsigned short)v2[2]) + bf2f((unsigned short)v3[2]);
    a3 += bf2f((unsigned short)v0[3]) + bf2f((unsigned short)v1[3]) + bf2f((unsigned short)v2[3]) + bf2f((unsigned short)v3[3]);
  }
  for (; i < end; ++i) {
    short4v v = *(const short4v*)&xsb[(size_t)edge_src[i] * D + t * 4];
    a0 += bf2f((unsigned short)v[0]); a1 += bf2f((unsigned short)v[1]);
    a2 += bf2f((unsigned short)v[2]); a3 += bf2f((unsigned short)v[3]);
  }
  int deg = end - start;
  float inv = 1.f / (float)(deg > 0 ? deg : 1);
  short4v r;
  r[0] = (short)f2bf(a0 * inv); r[1] = (short)f2bf(a1 * inv);
  r[2] = (short)f2bf(a2 * inv); r[3] = (short)f2bf(a3 * inv);
  *(short4v*)&aggr[(size_t)node * D + t * 4] = r;
}

// ---- f32 fallback aggr (aggr lives in d_out) ----------------------------
__global__ void aggr_f32_kernel(const float* __restrict__ xsrc, const int* __restrict__ offsets,
                                const int* __restrict__ edge_src, float* __restrict__ aggr) {
  int node = blockIdx.x;
  int t = threadIdx.x;
  int start = offsets[node], end = offsets[node + 1];
  float acc = 0.f;
  int i = start;
  for (; i + 4 <= end; i += 4) {
    int s0 = edge_src[i], s1 = edge_src[i + 1], s2 = edge_src[i + 2], s3 = edge_src[i + 3];
    acc += xsrc[(size_t)s0 * D + t];
    acc += xsrc[(size_t)s1 * D + t];
    acc += xsrc[(size_t)s2 * D + t];
    acc += xsrc[(size_t)s3 * D + t];
  }
  for (; i < end; ++i) acc += xsrc[(size_t)edge_src[i] * D + t];
  int deg = end - start;
  aggr[(size_t)node * D + t] = acc / (float)(deg > 0 ? deg : 1);
}

// ---- GEMM v3: 256x256 tile, K=512 in 8 chunks of 64, double-buffered ----
// 512 threads = 8 waves (2M x 4N). Each wave owns a 128x64 output sub-tile.
// A chunk 256x64 bf16 = 32KB; B chunk 256(oc)x64 bf16 = 32KB; x2 buffers = 128KB.
// LDS layout: row-major rows of 8x16B chunks, phys_chunk = logical ^ (row&7).
// Chunks 0-3: A from aggr (bf16) via global_load_lds, source pre-swizzled.
// Chunks 4-7: A from x_tgt (f32) reg-staged: load early, cvt+ds_write late (T14).
// B always from Wt via global_load_lds.
__global__ __launch_bounds__(512, 2) void gemm256_kernel(const unsigned short* __restrict__ aggr,
                                                         const float* __restrict__ xtgt,
                                                         const unsigned short* __restrict__ Wt,
                                                         const float* __restrict__ bias,
                                                         float* __restrict__ out, int n_tgt) {
  __shared__ __align__(16) unsigned short Abuf[2][16384];   // 32KB each
  __shared__ __align__(16) unsigned short Bbuf[2][16384];
  int t = threadIdx.x;
  int lane = t & 63, wid = t >> 6;
  int lr = lane & 15, lq = lane >> 4;
  int wr = wid >> 2, wc = wid & 3;
  int mbase = blockIdx.x * 256;

  floatx4 acc[8][4];
#pragma unroll
  for (int mt = 0; mt < 8; ++mt)
#pragma unroll
    for (int nt = 0; nt < 4; ++nt) acc[mt][nt] = (floatx4){0.f, 0.f, 0.f, 0.f};

  floatx4 st[8];   // reg-staging for x_tgt chunks

  // --- staging helpers (all inlined) ---
  auto stageA_gld = [&](int c, int buf) {         // aggr chunks (kbase = c*64 < 256)
    int kbase = c * 64;
#pragma unroll
    for (int r = 0; r < 4; ++r) {
      int s = wid * 256 + r * 64 + lane;
      int row = s >> 3, ch = s & 7;               // ch = physical 16B slot
      int grow = mbase + row; if (grow >= n_tgt) grow = n_tgt - 1;
      const unsigned short* src = aggr + (size_t)grow * 256 + kbase + ((ch ^ (row & 7)) * 8);
      gld_lds16(src, &Abuf[buf][(size_t)(wid * 256 + r * 64) * 8]);
    }
  };
  auto stageB_gld = [&](int c, int buf) {
    int kbase = c * 64;
#pragma unroll
    for (int r = 0; r < 4; ++r) {
      int s = wid * 256 + r * 64 + lane;
      int oc = s >> 3, ch = s & 7;
      const unsigned short* src = Wt + (size_t)oc * 512 + kbase + ((ch ^ (oc & 7)) * 8);
      gld_lds16(src, &Bbuf[buf][(size_t)(wid * 256 + r * 64) * 8]);
    }
  };
  auto loadX = [&](int c) {                       // x_tgt chunks (c >= 4)
    int koff = c * 64 - 256;
#pragma unroll
    for (int r = 0; r < 4; ++r) {
      int s = r * 512 + t;
      int row = s >> 3, ch = s & 7;
      int grow = mbase + row; if (grow >= n_tgt) grow = n_tgt - 1;
      const float* src = xtgt + (size_t)grow * 256 + koff + ch * 8;
      st[2 * r]     = *(const floatx4*)src;
      st[2 * r + 1] = *(const floatx4*)(src + 4);
    }
  };
  auto writeX = [&](int buf) {
#pragma unroll
    for (int r = 0; r < 4; ++r) {
      int s = r * 512 + t;
      int row = s >> 3, ch = s & 7;
      short8 v;
      v[0] = (short)f2bf(st[2 * r][0]); v[1] = (short)f2bf(st[2 * r][1]);
      v[2] = (short)f2bf(st[2 * r][2]); v[3] = (short)f2bf(st[2 * r][3]);
      v[4] = (short)f2bf(st[2 * r + 1][0]); v[5] = (short)f2bf(st[2 * r + 1][1]);
      v[6] = (short)f2bf(st[2 * r + 1][2]); v[7] = (short)f2bf(st[2 * r + 1][3]);
      *(short8*)&Abuf[buf][(size_t)(row * 8 + (ch ^ (row & 7))) * 8] = v;
    }
  };
  auto compute = [&](int buf) {
#pragma unroll
    for (int ks2 = 0; ks2 < 2; ++ks2) {
      short8 b[4];
#pragma unroll
      for (int nt = 0; nt < 4; ++nt) {
        int oc = wc * 64 + nt * 16 + lr;
        int phys = (ks2 * 4 + lq) ^ (oc & 7);
        b[nt] = *(const short8*)&Bbuf[buf][(size_t)(oc * 8 + phys) * 8];
      }
#pragma unroll
      for (int mt = 0; mt < 8; ++mt) {
        int row = wr * 128 + mt * 16 + lr;
        int phys = (ks2 * 4 + lq) ^ (row & 7);
        short8 a = *(const short8*)&Abuf[buf][(size_t)(row * 8 + phys) * 8];
#pragma unroll
        for (int nt = 0; nt < 4; ++nt)
          acc[mt][nt] = __builtin_amdgcn_mfma_f32_16x16x32_bf16(a, b[nt], acc[mt][nt], 0, 0, 0);
      }
    }
  };

  // --- prologue: stage chunk 0 ---
  stageA_gld(0, 0);
  stageB_gld(0, 0);
  __syncthreads();

  int cur = 0;
#pragma unroll
  for (int c = 0; c < 8; ++c) {
    int nxt = cur ^ 1;
    if (c + 1 < 8) {
      stageB_gld(c + 1, nxt);
      if (c + 1 < 4) stageA_gld(c + 1, nxt);
      else loadX(c + 1);                 // issue loads early...
    }
    compute(cur);
    if (c + 1 >= 4 && c + 1 < 8) writeX(nxt);   // ...write late (T14)
    __syncthreads();
    cur = nxt;
  }

  // --- epilogue: D frag row=(lq*4+r4), col=lr ---
#pragma unroll
  for (int nt = 0; nt < 4; ++nt) {
    int oc = wc * 64 + nt * 16 + lr;
    float bv = bias[oc];
#pragma unroll
    for (int mt = 0; mt < 8; ++mt) {
#pragma unroll
      for (int r4 = 0; r4 < 4; ++r4) {
        int node = mbase + wr * 128 + mt * 16 + lq * 4 + r4;
        if (node < n_tgt) out[(size_t)node * D + oc] = acc[mt][nt][r4] + bv;
      }
    }
  }
}

// ---- fallback fused GEMM (f32 aggr in d_out), 64-row tile ---------------
__global__ __launch_bounds__(256) void gemm_fb_kernel(const float* __restrict__ aggrp,
                                                      const float* __restrict__ xtgt,
                                                      const unsigned short* __restrict__ Wt,
                                                      const float* __restrict__ bias,
                                                      float* __restrict__ out, int n_tgt) {
  __shared__ __align__(16) unsigned short A_lds[64 * 256];
  int t = threadIdx.x;
  int mbase = blockIdx.x * 64;
  int lane = t & 63, w = t >> 6;
  int lr = lane & 15, lq = lane >> 4;

  floatx4 acc[4][4];
#pragma unroll
  for (int mt = 0; mt < 4; ++mt)
#pragma unroll
    for (int nt = 0; nt < 4; ++nt) acc[mt][nt] = (floatx4){0.f, 0.f, 0.f, 0.f};

  const unsigned short* WtW = Wt + ((size_t)(64 * w + lr)) * 512 + lq * 8;

  for (int ph = 0; ph < 2; ++ph) {
    const float* srcbase = ph == 0 ? aggrp : xtgt;
#pragma unroll
    for (int it = 0; it < 8; ++it) {
      int chunk = it * 256 + t;
      int r = chunk >> 5, c = chunk & 31;
      int node = mbase + r;
      floatx4 f0 = {0.f, 0.f, 0.f, 0.f}, f1 = {0.f, 0.f, 0.f, 0.f};
      if (node < n_tgt) {
        f0 = *(const floatx4*)&srcbase[(size_t)node * D + c * 8];
        f1 = *(const floatx4*)&srcbase[(size_t)node * D + c * 8 + 4];
      }
      short8 v;
      v[0] = (short)f2bf(f0[0]); v[1] = (short)f2bf(f0[1]);
      v[2] = (short)f2bf(f0[2]); v[3] = (short)f2bf(f0[3]);
      v[4] = (short)f2bf(f1[0]); v[5] = (short)f2bf(f1[1]);
      v[6] = (short)f2bf(f1[2]); v[7] = (short)f2bf(f1[3]);
      int sc = c ^ (r & 7);
      *(short8*)&A_lds[r * 256 + sc * 8] = v;
    }
    __syncthreads();
#pragma unroll
    for (int ks = 0; ks < 8; ++ks) {
      short8 a[4], b[4];
#pragma unroll
      for (int mt = 0; mt < 4; ++mt) {
        int row = 16 * mt + lr;
        int chunk = (ks * 4 + lq) ^ (row & 7);
        a[mt] = *(const short8*)&A_lds[row * 256 + chunk * 8];
      }
#pragma unroll
      for (int nt = 0; nt < 4; ++nt)
        b[nt] = *(const short8*)&WtW[(size_t)nt * 16 * 512 + (ph * 8 + ks) * 32];
#pragma unroll
      for (int mt = 0; mt < 4; ++mt)
#pragma unroll
        for (int nt = 0; nt < 4; ++nt)
          acc[mt][nt] = __builtin_amdgcn_mfma_f32_16x16x32_bf16(a[mt], b[nt], acc[mt][nt], 0, 0, 0);
    }
    __syncthreads();
  }

#pragma unroll
  for (int nt = 0; nt < 4; ++nt) {
    int oc = 64 * w + 16 * nt + lr;
    float bv = bias[oc];
#pragma unroll
    for (int mt = 0; mt < 4; ++mt) {
#pragma unroll
      for (int r4 = 0; r4 < 4; ++r4) {
        int node = mbase + 16 * mt + lq * 4 + r4;
        if (node < n_tgt) out[(size_t)node * D + oc] = acc[mt][nt][r4] + bv;
      }
    }
  }
}

extern "C" void kernel_launch(void* const* d_in, const int* in_sizes, int n_in,
                              void* d_out, int out_size, void* d_ws, size_t ws_size,
                              hipStream_t stream) {
  const float* x_src = (const float*)d_in[0];
  const float* x_tgt = (const float*)d_in[1];
  const void* ei = d_in[2];
  const float* W_l = (const float*)d_in[3];
  const float* b_l = (const float*)d_in[4];
  const float* W_r = (const float*)d_in[5];
  float* out = (float*)d_out;

  const int N_s = in_sizes[0] / D;     // source nodes
  const int N_t = in_sizes[1] / D;     // target nodes
  const int E = in_sizes[2] / 2;       // edges

  char* ws = (char*)d_ws;
  size_t o = 0;
  auto alloc = [&](size_t bytes) { size_t cur = o; o = (o + bytes + 255) & ~(size_t)255; return cur; };
  int* flag              = (int*)(ws + alloc(4));
  int* counts            = (int*)(ws + alloc((size_t)N_t * 4));
  int* offsets           = (int*)(ws + alloc(((size_t)N_t + 1) * 4));
  int* cursor            = (int*)(ws + alloc((size_t)N_t * 4));
  size_t zero_end        = o;
  int SB = (N_t + 1023) / 1024;
  int* bsum              = (int*)(ws + alloc(((size_t)SB) * 4));
  int* boff              = (int*)(ws + alloc(((size_t)SB + 1) * 4));
  int* edge_src          = (int*)(ws + alloc((size_t)E * 4));
  unsigned short* Wt     = (unsigned short*)(ws + alloc((size_t)256 * 512 * 2));
  size_t base_end        = o;
  unsigned short* xsrc_b = (unsigned short*)(ws + alloc((size_t)N_s * D * 2));
  unsigned short* aggr_b = (unsigned short*)(ws + alloc((size_t)N_t * D * 2));
  size_t bf16_end        = o;

  bool bf16_path = (ws_size >= bf16_end);
  (void)base_end;

  hipMemsetAsync(ws, 0, zero_end, stream);

  int eb = (E + 255) / 256;
  detect_kernel<<<1, 64, 0, stream>>>((const int*)ei, flag);
  count_kernel<<<eb, 256, 0, stream>>>(ei, flag, counts, E, N_t);
  scan_blocksum_kernel<<<SB, 256, 0, stream>>>(counts, bsum, N_t);
  scan_kernel<<<1, 1024, 0, stream>>>(bsum, boff, SB);
  scan_apply_kernel<<<SB, 256, 0, stream>>>(counts, boff, offsets, N_t);
  fill_kernel<<<eb, 256, 0, stream>>>(ei, flag, offsets, cursor, edge_src, E, N_t);
  wt_kernel<<<512, 256, 0, stream>>>(W_l, W_r, Wt);

  if (bf16_path) {
    long long n8 = (long long)N_s * D / 8;
    xcast_kernel<<<(int)((n8 + 255) / 256), 256, 0, stream>>>(x_src, xsrc_b, n8);
    aggr_bf_kernel<<<N_t, 64, 0, stream>>>(xsrc_b, offsets, edge_src, aggr_b);
    gemm256_kernel<<<(N_t + 255) / 256, 512, 0, stream>>>(aggr_b, x_tgt, Wt, b_l, out, N_t);
  } else {
    aggr_f32_kernel<<<N_t, 256, 0, stream>>>(x_src, offsets, edge_src, out);
    gemm_fb_kernel<<<(N_t + 63) / 64, 256, 0, stream>>>(out, x_tgt, Wt, b_l, out, N_t);
  }
}

// Round 7
// 386.636 us; speedup vs baseline: 1.1319x; 1.0081x over previous
//
#include <hip/hip_runtime.h>
#include <hip/hip_bf16.h>

#define D 256

typedef __attribute__((ext_vector_type(8))) short short8;
typedef __attribute__((ext_vector_type(4))) short short4v;
typedef __attribute__((ext_vector_type(4))) float floatx4;
typedef __attribute__((ext_vector_type(4))) int intx4;

static __device__ __forceinline__ unsigned short f2bf(float f) {
  unsigned int u = __builtin_bit_cast(unsigned int, f);
  u += 0x7FFFu + ((u >> 16) & 1u);   // RNE to bf16
  return (unsigned short)(u >> 16);
}
static __device__ __forceinline__ float bf2f(unsigned short s) {
  unsigned int u = ((unsigned int)s) << 16;
  return __builtin_bit_cast(float, u);
}

static __device__ __forceinline__ void gld_lds16(const unsigned short* g, unsigned short* l) {
  __builtin_amdgcn_global_load_lds(
      (const __attribute__((address_space(1))) unsigned int*)g,
      (__attribute__((address_space(3))) unsigned int*)l, 16, 0, 0);
}

// ---- detect int64 vs int32 edge_index storage (one wave) ---------------
__global__ void detect_kernel(const int* __restrict__ ei32, int* __restrict__ flag) {
  int lane = threadIdx.x;
  int v = ei32[2 * lane + 1];
  unsigned long long nz = __ballot(v != 0);
  if (lane == 0) *flag = (nz == 0ULL) ? 1 : 0;   // 1 => int64 layout
}

static __device__ __forceinline__ int edge_at(const void* ei, int is64, long long idx) {
  return is64 ? (int)((const long long*)ei)[idx] : ((const int*)ei)[idx];
}

// ---- CSR build ---------------------------------------------------------
__global__ void count_kernel(const void* __restrict__ ei, const int* __restrict__ flag,
                             int* __restrict__ counts, int E, int N) {
  int is64 = *flag;
  int e = blockIdx.x * blockDim.x + threadIdx.x;
  if (e < E) {
    int c = edge_at(ei, is64, (long long)E + e);
    if ((unsigned)c < (unsigned)N) atomicAdd(&counts[c], 1);
  }
}

__global__ __launch_bounds__(256) void scan_blocksum_kernel(const int* __restrict__ counts,
                                                            int* __restrict__ bsum, int n) {
  __shared__ int sh[256];
  int b = blockIdx.x, t = threadIdx.x;
  int base = b * 1024 + t * 4;
  int s = 0;
  if (base + 3 < n) {
    intx4 v = *(const intx4*)&counts[base];
    s = v[0] + v[1] + v[2] + v[3];
  } else {
    for (int j = 0; j < 4; ++j) if (base + j < n) s += counts[base + j];
  }
  sh[t] = s;
  __syncthreads();
  for (int d = 128; d > 0; d >>= 1) {
    if (t < d) sh[t] += sh[t + d];
    __syncthreads();
  }
  if (t == 0) bsum[b] = sh[0];
}

__global__ void scan_kernel(const int* __restrict__ counts, int* __restrict__ offsets, int n) {
  __shared__ int part[1024];
  int t = threadIdx.x;
  int CH = (n + 1023) / 1024;
  int lo = t * CH;
  int hi = lo + CH; if (hi > n) hi = n;
  int s = 0;
  for (int i = lo; i < hi; ++i) s += counts[i];
  part[t] = s;
  __syncthreads();
  for (int d = 1; d < 1024; d <<= 1) {
    int v = (t >= d) ? part[t - d] : 0;
    __syncthreads();
    part[t] += v;
    __syncthreads();
  }
  int run = (t == 0) ? 0 : part[t - 1];
  for (int i = lo; i < hi; ++i) { offsets[i] = run; run += counts[i]; }
  if (hi == n) offsets[n] = run;
}

__global__ __launch_bounds__(256) void scan_apply_kernel(const int* __restrict__ counts,
                                                         const int* __restrict__ boff,
                                                         int* __restrict__ offsets, int n) {
  __shared__ int sh[256];
  int b = blockIdx.x, t = threadIdx.x;
  int base = b * 1024 + t * 4;
  int c0 = (base + 0 < n) ? counts[base + 0] : 0;
  int c1 = (base + 1 < n) ? counts[base + 1] : 0;
  int c2 = (base + 2 < n) ? counts[base + 2] : 0;
  int c3 = (base + 3 < n) ? counts[base + 3] : 0;
  sh[t] = c0 + c1 + c2 + c3;
  __syncthreads();
  for (int d = 1; d < 256; d <<= 1) {
    int v = (t >= d) ? sh[t - d] : 0;
    __syncthreads();
    sh[t] += v;
    __syncthreads();
  }
  int excl = (t == 0 ? 0 : sh[t - 1]) + boff[b];
  if (base + 0 < n) offsets[base + 0] = excl;
  if (base + 1 < n) offsets[base + 1] = excl + c0;
  if (base + 2 < n) offsets[base + 2] = excl + c0 + c1;
  if (base + 3 < n) offsets[base + 3] = excl + c0 + c1 + c2;
  if (b == (int)gridDim.x - 1 && t == 255) offsets[n] = boff[gridDim.x];
}

__global__ void fill_kernel(const void* __restrict__ ei, const int* __restrict__ flag,
                            const int* __restrict__ offsets, int* __restrict__ cursor,
                            int* __restrict__ edge_src, int E, int N) {
  int is64 = *flag;
  int e = blockIdx.x * blockDim.x + threadIdx.x;
  if (e < E) {
    int c = edge_at(ei, is64, (long long)E + e);
    int s = edge_at(ei, is64, (long long)e);
    if ((unsigned)c < (unsigned)N && (unsigned)s < (unsigned)N) {
      int pos = atomicAdd(&cursor[c], 1);
      edge_src[offsets[c] + pos] = s;
    }
  }
}

// ---- W transpose + bf16: Wt[oc][k] (k<256 -> W_l, else W_r) ------------
__global__ void wt_kernel(const float* __restrict__ Wl, const float* __restrict__ Wr,
                          unsigned short* __restrict__ Wt) {
  int idx = blockIdx.x * blockDim.x + threadIdx.x;
  int oc = idx >> 9, k = idx & 511;
  float v = (k < 256) ? Wl[k * 256 + oc] : Wr[(k - 256) * 256 + oc];
  Wt[idx] = f2bf(v);
}

// ---- x_src f32 -> bf16 (8 elems/thread) --------------------------------
__global__ void xcast_kernel(const float* __restrict__ x, unsigned short* __restrict__ xb,
                             long long n8) {
  long long i = (long long)blockIdx.x * blockDim.x + threadIdx.x;
  if (i >= n8) return;
  floatx4 f0 = *(const floatx4*)&x[i * 8];
  floatx4 f1 = *(const floatx4*)&x[i * 8 + 4];
  short8 v;
  v[0] = (short)f2bf(f0[0]); v[1] = (short)f2bf(f0[1]);
  v[2] = (short)f2bf(f0[2]); v[3] = (short)f2bf(f0[3]);
  v[4] = (short)f2bf(f1[0]); v[5] = (short)f2bf(f1[1]);
  v[6] = (short)f2bf(f1[2]); v[7] = (short)f2bf(f1[3]);
  *(short8*)&xb[i * 8] = v;
}

// ---- scatter-mean v2: 4 waves/block, 1 node/wave, 2 edges per wave-load --
// lanes 0-31 = even edges, 32-63 = odd edges; each lane covers 8 features.
// Batched 8-edges/iter with 0/1-mask fmaf (no ragged tail), then xor-32 reduce.
__global__ __launch_bounds__(256) void aggr_bf2_kernel(const unsigned short* __restrict__ xsb,
                                                       const int* __restrict__ offsets,
                                                       const int* __restrict__ edge_src,
                                                       unsigned short* __restrict__ aggr,
                                                       int n_tgt) {
  int node = blockIdx.x * 4 + (threadIdx.x >> 6);
  if (node >= n_tgt) return;
  int lane = threadIdx.x & 63;
  int half = lane >> 5;
  int fb = (lane & 31) * 8;              // feature base, 8 bf16 = 16B per lane
  int start = offsets[node], end = offsets[node + 1];
  int deg = end - start;

  float a[8];
#pragma unroll
  for (int k = 0; k < 8; ++k) a[k] = 0.f;

  if (deg > 0) {
    int last = end - 1;
    for (int i = start + half; i < end; i += 8) {
      int e1 = i + 2, e2 = i + 4, e3 = i + 6;
      int s0 = edge_src[i];
      int s1 = edge_src[e1 < end ? e1 : last];
      int s2 = edge_src[e2 < end ? e2 : last];
      int s3 = edge_src[e3 < end ? e3 : last];
      float m1 = e1 < end ? 1.f : 0.f;
      float m2 = e2 < end ? 1.f : 0.f;
      float m3 = e3 < end ? 1.f : 0.f;
      short8 v0 = *(const short8*)&xsb[(size_t)s0 * D + fb];
      short8 v1 = *(const short8*)&xsb[(size_t)s1 * D + fb];
      short8 v2 = *(const short8*)&xsb[(size_t)s2 * D + fb];
      short8 v3 = *(const short8*)&xsb[(size_t)s3 * D + fb];
#pragma unroll
      for (int k = 0; k < 8; ++k) {
        a[k] += bf2f((unsigned short)v0[k]);
        a[k] = fmaf(bf2f((unsigned short)v1[k]), m1, a[k]);
        a[k] = fmaf(bf2f((unsigned short)v2[k]), m2, a[k]);
        a[k] = fmaf(bf2f((unsigned short)v3[k]), m3, a[k]);
      }
    }
  }

  // combine the two half-wave partial sums
#pragma unroll
  for (int k = 0; k < 8; ++k) a[k] += __shfl_xor(a[k], 32);

  if (half == 0) {
    float inv = 1.f / (float)(deg > 0 ? deg : 1);
    short8 r;
#pragma unroll
    for (int k = 0; k < 8; ++k) r[k] = (short)f2bf(a[k] * inv);
    *(short8*)&aggr[(size_t)node * D + fb] = r;
  }
}

// ---- f32 fallback aggr (aggr lives in d_out) ----------------------------
__global__ void aggr_f32_kernel(const float* __restrict__ xsrc, const int* __restrict__ offsets,
                                const int* __restrict__ edge_src, float* __restrict__ aggr) {
  int node = blockIdx.x;
  int t = threadIdx.x;
  int start = offsets[node], end = offsets[node + 1];
  float acc = 0.f;
  int i = start;
  for (; i + 4 <= end; i += 4) {
    int s0 = edge_src[i], s1 = edge_src[i + 1], s2 = edge_src[i + 2], s3 = edge_src[i + 3];
    acc += xsrc[(size_t)s0 * D + t];
    acc += xsrc[(size_t)s1 * D + t];
    acc += xsrc[(size_t)s2 * D + t];
    acc += xsrc[(size_t)s3 * D + t];
  }
  for (; i < end; ++i) acc += xsrc[(size_t)edge_src[i] * D + t];
  int deg = end - start;
  aggr[(size_t)node * D + t] = acc / (float)(deg > 0 ? deg : 1);
}

// ---- GEMM v3: 256x256 tile, K=512 in 8 chunks of 64, double-buffered ----
__global__ __launch_bounds__(512, 2) void gemm256_kernel(const unsigned short* __restrict__ aggr,
                                                         const float* __restrict__ xtgt,
                                                         const unsigned short* __restrict__ Wt,
                                                         const float* __restrict__ bias,
                                                         float* __restrict__ out, int n_tgt) {
  __shared__ __align__(16) unsigned short Abuf[2][16384];   // 32KB each
  __shared__ __align__(16) unsigned short Bbuf[2][16384];
  int t = threadIdx.x;
  int lane = t & 63, wid = t >> 6;
  int lr = lane & 15, lq = lane >> 4;
  int wr = wid >> 2, wc = wid & 3;
  int mbase = blockIdx.x * 256;

  floatx4 acc[8][4];
#pragma unroll
  for (int mt = 0; mt < 8; ++mt)
#pragma unroll
    for (int nt = 0; nt < 4; ++nt) acc[mt][nt] = (floatx4){0.f, 0.f, 0.f, 0.f};

  floatx4 st[8];   // reg-staging for x_tgt chunks

  auto stageA_gld = [&](int c, int buf) {
    int kbase = c * 64;
#pragma unroll
    for (int r = 0; r < 4; ++r) {
      int s = wid * 256 + r * 64 + lane;
      int row = s >> 3, ch = s & 7;
      int grow = mbase + row; if (grow >= n_tgt) grow = n_tgt - 1;
      const unsigned short* src = aggr + (size_t)grow * 256 + kbase + ((ch ^ (row & 7)) * 8);
      gld_lds16(src, &Abuf[buf][(size_t)(wid * 256 + r * 64) * 8]);
    }
  };
  auto stageB_gld = [&](int c, int buf) {
    int kbase = c * 64;
#pragma unroll
    for (int r = 0; r < 4; ++r) {
      int s = wid * 256 + r * 64 + lane;
      int oc = s >> 3, ch = s & 7;
      const unsigned short* src = Wt + (size_t)oc * 512 + kbase + ((ch ^ (oc & 7)) * 8);
      gld_lds16(src, &Bbuf[buf][(size_t)(wid * 256 + r * 64) * 8]);
    }
  };
  auto loadX = [&](int c) {
    int koff = c * 64 - 256;
#pragma unroll
    for (int r = 0; r < 4; ++r) {
      int s = r * 512 + t;
      int row = s >> 3, ch = s & 7;
      int grow = mbase + row; if (grow >= n_tgt) grow = n_tgt - 1;
      const float* src = xtgt + (size_t)grow * 256 + koff + ch * 8;
      st[2 * r]     = *(const floatx4*)src;
      st[2 * r + 1] = *(const floatx4*)(src + 4);
    }
  };
  auto writeX = [&](int buf) {
#pragma unroll
    for (int r = 0; r < 4; ++r) {
      int s = r * 512 + t;
      int row = s >> 3, ch = s & 7;
      short8 v;
      v[0] = (short)f2bf(st[2 * r][0]); v[1] = (short)f2bf(st[2 * r][1]);
      v[2] = (short)f2bf(st[2 * r][2]); v[3] = (short)f2bf(st[2 * r][3]);
      v[4] = (short)f2bf(st[2 * r + 1][0]); v[5] = (short)f2bf(st[2 * r + 1][1]);
      v[6] = (short)f2bf(st[2 * r + 1][2]); v[7] = (short)f2bf(st[2 * r + 1][3]);
      *(short8*)&Abuf[buf][(size_t)(row * 8 + (ch ^ (row & 7))) * 8] = v;
    }
  };
  auto compute = [&](int buf) {
#pragma unroll
    for (int ks2 = 0; ks2 < 2; ++ks2) {
      short8 b[4];
#pragma unroll
      for (int nt = 0; nt < 4; ++nt) {
        int oc = wc * 64 + nt * 16 + lr;
        int phys = (ks2 * 4 + lq) ^ (oc & 7);
        b[nt] = *(const short8*)&Bbuf[buf][(size_t)(oc * 8 + phys) * 8];
      }
#pragma unroll
      for (int mt = 0; mt < 8; ++mt) {
        int row = wr * 128 + mt * 16 + lr;
        int phys = (ks2 * 4 + lq) ^ (row & 7);
        short8 a = *(const short8*)&Abuf[buf][(size_t)(row * 8 + phys) * 8];
#pragma unroll
        for (int nt = 0; nt < 4; ++nt)
          acc[mt][nt] = __builtin_amdgcn_mfma_f32_16x16x32_bf16(a, b[nt], acc[mt][nt], 0, 0, 0);
      }
    }
  };

  stageA_gld(0, 0);
  stageB_gld(0, 0);
  __syncthreads();

  int cur = 0;
#pragma unroll
  for (int c = 0; c < 8; ++c) {
    int nxt = cur ^ 1;
    if (c + 1 < 8) {
      stageB_gld(c + 1, nxt);
      if (c + 1 < 4) stageA_gld(c + 1, nxt);
      else loadX(c + 1);
    }
    compute(cur);
    if (c + 1 >= 4 && c + 1 < 8) writeX(nxt);
    __syncthreads();
    cur = nxt;
  }

#pragma unroll
  for (int nt = 0; nt < 4; ++nt) {
    int oc = wc * 64 + nt * 16 + lr;
    float bv = bias[oc];
#pragma unroll
    for (int mt = 0; mt < 8; ++mt) {
#pragma unroll
      for (int r4 = 0; r4 < 4; ++r4) {
        int node = mbase + wr * 128 + mt * 16 + lq * 4 + r4;
        if (node < n_tgt) out[(size_t)node * D + oc] = acc[mt][nt][r4] + bv;
      }
    }
  }
}

// ---- fallback fused GEMM (f32 aggr in d_out), 64-row tile ---------------
__global__ __launch_bounds__(256) void gemm_fb_kernel(const float* __restrict__ aggrp,
                                                      const float* __restrict__ xtgt,
                                                      const unsigned short* __restrict__ Wt,
                                                      const float* __restrict__ bias,
                                                      float* __restrict__ out, int n_tgt) {
  __shared__ __align__(16) unsigned short A_lds[64 * 256];
  int t = threadIdx.x;
  int mbase = blockIdx.x * 64;
  int lane = t & 63, w = t >> 6;
  int lr = lane & 15, lq = lane >> 4;

  floatx4 acc[4][4];
#pragma unroll
  for (int mt = 0; mt < 4; ++mt)
#pragma unroll
    for (int nt = 0; nt < 4; ++nt) acc[mt][nt] = (floatx4){0.f, 0.f, 0.f, 0.f};

  const unsigned short* WtW = Wt + ((size_t)(64 * w + lr)) * 512 + lq * 8;

  for (int ph = 0; ph < 2; ++ph) {
    const float* srcbase = ph == 0 ? aggrp : xtgt;
#pragma unroll
    for (int it = 0; it < 8; ++it) {
      int chunk = it * 256 + t;
      int r = chunk >> 5, c = chunk & 31;
      int node = mbase + r;
      floatx4 f0 = {0.f, 0.f, 0.f, 0.f}, f1 = {0.f, 0.f, 0.f, 0.f};
      if (node < n_tgt) {
        f0 = *(const floatx4*)&srcbase[(size_t)node * D + c * 8];
        f1 = *(const floatx4*)&srcbase[(size_t)node * D + c * 8 + 4];
      }
      short8 v;
      v[0] = (short)f2bf(f0[0]); v[1] = (short)f2bf(f0[1]);
      v[2] = (short)f2bf(f0[2]); v[3] = (short)f2bf(f0[3]);
      v[4] = (short)f2bf(f1[0]); v[5] = (short)f2bf(f1[1]);
      v[6] = (short)f2bf(f1[2]); v[7] = (short)f2bf(f1[3]);
      int sc = c ^ (r & 7);
      *(short8*)&A_lds[r * 256 + sc * 8] = v;
    }
    __syncthreads();
#pragma unroll
    for (int ks = 0; ks < 8; ++ks) {
      short8 a[4], b[4];
#pragma unroll
      for (int mt = 0; mt < 4; ++mt) {
        int row = 16 * mt + lr;
        int chunk = (ks * 4 + lq) ^ (row & 7);
        a[mt] = *(const short8*)&A_lds[row * 256 + chunk * 8];
      }
#pragma unroll
      for (int nt = 0; nt < 4; ++nt)
        b[nt] = *(const short8*)&WtW[(size_t)nt * 16 * 512 + (ph * 8 + ks) * 32];
#pragma unroll
      for (int mt = 0; mt < 4; ++mt)
#pragma unroll
        for (int nt = 0; nt < 4; ++nt)
          acc[mt][nt] = __builtin_amdgcn_mfma_f32_16x16x32_bf16(a[mt], b[nt], acc[mt][nt], 0, 0, 0);
    }
    __syncthreads();
  }

#pragma unroll
  for (int nt = 0; nt < 4; ++nt) {
    int oc = 64 * w + 16 * nt + lr;
    float bv = bias[oc];
#pragma unroll
    for (int mt = 0; mt < 4; ++mt) {
#pragma unroll
      for (int r4 = 0; r4 < 4; ++r4) {
        int node = mbase + 16 * mt + lq * 4 + r4;
        if (node < n_tgt) out[(size_t)node * D + oc] = acc[mt][nt][r4] + bv;
      }
    }
  }
}

extern "C" void kernel_launch(void* const* d_in, const int* in_sizes, int n_in,
                              void* d_out, int out_size, void* d_ws, size_t ws_size,
                              hipStream_t stream) {
  const float* x_src = (const float*)d_in[0];
  const float* x_tgt = (const float*)d_in[1];
  const void* ei = d_in[2];
  const float* W_l = (const float*)d_in[3];
  const float* b_l = (const float*)d_in[4];
  const float* W_r = (const float*)d_in[5];
  float* out = (float*)d_out;

  const int N_s = in_sizes[0] / D;     // source nodes
  const int N_t = in_sizes[1] / D;     // target nodes
  const int E = in_sizes[2] / 2;       // edges

  char* ws = (char*)d_ws;
  size_t o = 0;
  auto alloc = [&](size_t bytes) { size_t cur = o; o = (o + bytes + 255) & ~(size_t)255; return cur; };
  int* flag              = (int*)(ws + alloc(4));
  int* counts            = (int*)(ws + alloc((size_t)N_t * 4));
  int* offsets           = (int*)(ws + alloc(((size_t)N_t + 1) * 4));
  int* cursor            = (int*)(ws + alloc((size_t)N_t * 4));
  size_t zero_end        = o;
  int SB = (N_t + 1023) / 1024;
  int* bsum              = (int*)(ws + alloc(((size_t)SB) * 4));
  int* boff              = (int*)(ws + alloc(((size_t)SB + 1) * 4));
  int* edge_src          = (int*)(ws + alloc((size_t)E * 4));
  unsigned short* Wt     = (unsigned short*)(ws + alloc((size_t)256 * 512 * 2));
  size_t base_end        = o;
  unsigned short* xsrc_b = (unsigned short*)(ws + alloc((size_t)N_s * D * 2));
  unsigned short* aggr_b = (unsigned short*)(ws + alloc((size_t)N_t * D * 2));
  size_t bf16_end        = o;

  bool bf16_path = (ws_size >= bf16_end);
  (void)base_end;

  hipMemsetAsync(ws, 0, zero_end, stream);

  int eb = (E + 255) / 256;
  detect_kernel<<<1, 64, 0, stream>>>((const int*)ei, flag);
  count_kernel<<<eb, 256, 0, stream>>>(ei, flag, counts, E, N_t);
  scan_blocksum_kernel<<<SB, 256, 0, stream>>>(counts, bsum, N_t);
  scan_kernel<<<1, 1024, 0, stream>>>(bsum, boff, SB);
  scan_apply_kernel<<<SB, 256, 0, stream>>>(counts, boff, offsets, N_t);
  fill_kernel<<<eb, 256, 0, stream>>>(ei, flag, offsets, cursor, edge_src, E, N_t);
  wt_kernel<<<512, 256, 0, stream>>>(W_l, W_r, Wt);

  if (bf16_path) {
    long long n8 = (long long)N_s * D / 8;
    xcast_kernel<<<(int)((n8 + 255) / 256), 256, 0, stream>>>(x_src, xsrc_b, n8);
    aggr_bf2_kernel<<<(N_t + 3) / 4, 256, 0, stream>>>(xsrc_b, offsets, edge_src, aggr_b, N_t);
    gemm256_kernel<<<(N_t + 255) / 256, 512, 0, stream>>>(aggr_b, x_tgt, Wt, b_l, out, N_t);
  } else {
    aggr_f32_kernel<<<N_t, 256, 0, stream>>>(x_src, offsets, edge_src, out);
    gemm_fb_kernel<<<(N_t + 63) / 64, 256, 0, stream>>>(out, x_tgt, Wt, b_l, out, N_t);
  }
}

// Round 8
// 336.833 us; speedup vs baseline: 1.2993x; 1.1479x over previous
//
#include <hip/hip_runtime.h>
#include <hip/hip_bf16.h>

#define D 256

typedef __attribute__((ext_vector_type(8))) short short8;
typedef __attribute__((ext_vector_type(4))) float floatx4;
typedef __attribute__((ext_vector_type(4))) int intx4;

static __device__ __forceinline__ unsigned short f2bf(float f) {
  unsigned int u = __builtin_bit_cast(unsigned int, f);
  u += 0x7FFFu + ((u >> 16) & 1u);   // RNE to bf16
  return (unsigned short)(u >> 16);
}

static __device__ __forceinline__ void gld_lds16(const unsigned short* g, unsigned short* l) {
  __builtin_amdgcn_global_load_lds(
      (const __attribute__((address_space(1))) unsigned int*)g,
      (__attribute__((address_space(3))) unsigned int*)l, 16, 0, 0);
}

// ---- detect int64 vs int32 edge_index storage (one wave) ---------------
__global__ void detect_kernel(const int* __restrict__ ei32, int* __restrict__ flag) {
  int lane = threadIdx.x;
  int v = ei32[2 * lane + 1];
  unsigned long long nz = __ballot(v != 0);
  if (lane == 0) *flag = (nz == 0ULL) ? 1 : 0;   // 1 => int64 layout
}

static __device__ __forceinline__ int edge_at(const void* ei, int is64, long long idx) {
  return is64 ? (int)((const long long*)ei)[idx] : ((const int*)ei)[idx];
}

// ---- CSR build ---------------------------------------------------------
__global__ void count_kernel(const void* __restrict__ ei, const int* __restrict__ flag,
                             int* __restrict__ counts, int E, int N) {
  int is64 = *flag;
  int e = blockIdx.x * blockDim.x + threadIdx.x;
  if (e < E) {
    int c = edge_at(ei, is64, (long long)E + e);
    if ((unsigned)c < (unsigned)N) atomicAdd(&counts[c], 1);
  }
}

__global__ __launch_bounds__(256) void scan_blocksum_kernel(const int* __restrict__ counts,
                                                            int* __restrict__ bsum, int n) {
  __shared__ int sh[256];
  int b = blockIdx.x, t = threadIdx.x;
  int base = b * 1024 + t * 4;
  int s = 0;
  if (base + 3 < n) {
    intx4 v = *(const intx4*)&counts[base];
    s = v[0] + v[1] + v[2] + v[3];
  } else {
    for (int j = 0; j < 4; ++j) if (base + j < n) s += counts[base + j];
  }
  sh[t] = s;
  __syncthreads();
  for (int d = 128; d > 0; d >>= 1) {
    if (t < d) sh[t] += sh[t + d];
    __syncthreads();
  }
  if (t == 0) bsum[b] = sh[0];
}

__global__ void scan_kernel(const int* __restrict__ counts, int* __restrict__ offsets, int n) {
  __shared__ int part[1024];
  int t = threadIdx.x;
  int CH = (n + 1023) / 1024;
  int lo = t * CH;
  int hi = lo + CH; if (hi > n) hi = n;
  int s = 0;
  for (int i = lo; i < hi; ++i) s += counts[i];
  part[t] = s;
  __syncthreads();
  for (int d = 1; d < 1024; d <<= 1) {
    int v = (t >= d) ? part[t - d] : 0;
    __syncthreads();
    part[t] += v;
    __syncthreads();
  }
  int run = (t == 0) ? 0 : part[t - 1];
  for (int i = lo; i < hi; ++i) { offsets[i] = run; run += counts[i]; }
  if (hi == n) offsets[n] = run;
}

__global__ __launch_bounds__(256) void scan_apply_kernel(const int* __restrict__ counts,
                                                         const int* __restrict__ boff,
                                                         int* __restrict__ offsets, int n) {
  __shared__ int sh[256];
  int b = blockIdx.x, t = threadIdx.x;
  int base = b * 1024 + t * 4;
  int c0 = (base + 0 < n) ? counts[base + 0] : 0;
  int c1 = (base + 1 < n) ? counts[base + 1] : 0;
  int c2 = (base + 2 < n) ? counts[base + 2] : 0;
  int c3 = (base + 3 < n) ? counts[base + 3] : 0;
  sh[t] = c0 + c1 + c2 + c3;
  __syncthreads();
  for (int d = 1; d < 256; d <<= 1) {
    int v = (t >= d) ? sh[t - d] : 0;
    __syncthreads();
    sh[t] += v;
    __syncthreads();
  }
  int excl = (t == 0 ? 0 : sh[t - 1]) + boff[b];
  if (base + 0 < n) offsets[base + 0] = excl;
  if (base + 1 < n) offsets[base + 1] = excl + c0;
  if (base + 2 < n) offsets[base + 2] = excl + c0 + c1;
  if (base + 3 < n) offsets[base + 3] = excl + c0 + c1 + c2;
  if (b == (int)gridDim.x - 1 && t == 255) offsets[n] = boff[gridDim.x];
}

__global__ void fill_kernel(const void* __restrict__ ei, const int* __restrict__ flag,
                            const int* __restrict__ offsets, int* __restrict__ cursor,
                            int* __restrict__ edge_src, int E, int N) {
  int is64 = *flag;
  int e = blockIdx.x * blockDim.x + threadIdx.x;
  if (e < E) {
    int c = edge_at(ei, is64, (long long)E + e);
    int s = edge_at(ei, is64, (long long)e);
    if ((unsigned)c < (unsigned)N && (unsigned)s < (unsigned)N) {
      int pos = atomicAdd(&cursor[c], 1);
      edge_src[offsets[c] + pos] = s;
    }
  }
}

// ---- W transpose + bf16: Wt[oc][k] (k<256 -> W_l, else W_r) ------------
__global__ void wt_kernel(const float* __restrict__ Wl, const float* __restrict__ Wr,
                          unsigned short* __restrict__ Wt) {
  int idx = blockIdx.x * blockDim.x + threadIdx.x;
  int oc = idx >> 9, k = idx & 511;
  float v = (k < 256) ? Wl[k * 256 + oc] : Wr[(k - 256) * 256 + oc];
  Wt[idx] = f2bf(v);
}

// ---- x_src f32 -> fp8 e4m3 (16 elems/thread, HW cvt) --------------------
__global__ void xcast_f8_kernel(const float* __restrict__ x, unsigned int* __restrict__ xf8,
                                long long n16) {
  long long i = (long long)blockIdx.x * blockDim.x + threadIdx.x;
  if (i >= n16) return;
  const float* src = x + i * 16;
  intx4 w;
#pragma unroll
  for (int j = 0; j < 4; ++j) {
    floatx4 f = *(const floatx4*)(src + j * 4);
    int d = __builtin_amdgcn_cvt_pk_fp8_f32(f[0], f[1], 0, false);
    d = __builtin_amdgcn_cvt_pk_fp8_f32(f[2], f[3], d, true);
    w[j] = d;
  }
  *(intx4*)&xf8[i * 4] = w;
}

// ---- scatter-mean v3: fp8 gather, 4 waves/block, 1 node/wave ------------
// 16 lanes x 16B cover one 256B fp8 row; 64-lane wave = 4 edges per load.
// Batched 16 edges/iter (4 loads in flight), 0/1-mask fmaf, xor-16/32 reduce.
__global__ __launch_bounds__(256) void aggr_f8_kernel(const unsigned int* __restrict__ xf8,
                                                      const int* __restrict__ offsets,
                                                      const int* __restrict__ edge_src,
                                                      unsigned short* __restrict__ aggr,
                                                      int n_tgt) {
  int node = blockIdx.x * 4 + (threadIdx.x >> 6);
  if (node >= n_tgt) return;
  int lane = threadIdx.x & 63;
  int q = lane >> 4;                 // edge-offset group 0..3
  int fl = lane & 15;                // feature lane: feats fl*16 .. fl*16+15
  int start = offsets[node], end = offsets[node + 1];
  int deg = end - start;

  float a[16];
#pragma unroll
  for (int k = 0; k < 16; ++k) a[k] = 0.f;

  if (deg > 0) {
    int last = end - 1;
    for (int i = start + q; i < end; i += 16) {
      int e1 = i + 4, e2 = i + 8, e3 = i + 12;
      int s0 = edge_src[i];
      int s1 = edge_src[e1 < end ? e1 : last];
      int s2 = edge_src[e2 < end ? e2 : last];
      int s3 = edge_src[e3 < end ? e3 : last];
      float m1 = e1 < end ? 1.f : 0.f;
      float m2 = e2 < end ? 1.f : 0.f;
      float m3 = e3 < end ? 1.f : 0.f;
      intx4 w0 = *(const intx4*)&xf8[(size_t)s0 * 64 + fl * 4];
      intx4 w1 = *(const intx4*)&xf8[(size_t)s1 * 64 + fl * 4];
      intx4 w2 = *(const intx4*)&xf8[(size_t)s2 * 64 + fl * 4];
      intx4 w3 = *(const intx4*)&xf8[(size_t)s3 * 64 + fl * 4];
#pragma unroll
      for (int j = 0; j < 4; ++j) {
        {
          auto lo = __builtin_amdgcn_cvt_pk_f32_fp8(w0[j], false);
          auto hi = __builtin_amdgcn_cvt_pk_f32_fp8(w0[j], true);
          a[4 * j + 0] += lo[0]; a[4 * j + 1] += lo[1];
          a[4 * j + 2] += hi[0]; a[4 * j + 3] += hi[1];
        }
        {
          auto lo = __builtin_amdgcn_cvt_pk_f32_fp8(w1[j], false);
          auto hi = __builtin_amdgcn_cvt_pk_f32_fp8(w1[j], true);
          a[4 * j + 0] = fmaf(lo[0], m1, a[4 * j + 0]);
          a[4 * j + 1] = fmaf(lo[1], m1, a[4 * j + 1]);
          a[4 * j + 2] = fmaf(hi[0], m1, a[4 * j + 2]);
          a[4 * j + 3] = fmaf(hi[1], m1, a[4 * j + 3]);
        }
        {
          auto lo = __builtin_amdgcn_cvt_pk_f32_fp8(w2[j], false);
          auto hi = __builtin_amdgcn_cvt_pk_f32_fp8(w2[j], true);
          a[4 * j + 0] = fmaf(lo[0], m2, a[4 * j + 0]);
          a[4 * j + 1] = fmaf(lo[1], m2, a[4 * j + 1]);
          a[4 * j + 2] = fmaf(hi[0], m2, a[4 * j + 2]);
          a[4 * j + 3] = fmaf(hi[1], m2, a[4 * j + 3]);
        }
        {
          auto lo = __builtin_amdgcn_cvt_pk_f32_fp8(w3[j], false);
          auto hi = __builtin_amdgcn_cvt_pk_f32_fp8(w3[j], true);
          a[4 * j + 0] = fmaf(lo[0], m3, a[4 * j + 0]);
          a[4 * j + 1] = fmaf(lo[1], m3, a[4 * j + 1]);
          a[4 * j + 2] = fmaf(hi[0], m3, a[4 * j + 2]);
          a[4 * j + 3] = fmaf(hi[1], m3, a[4 * j + 3]);
        }
      }
    }
  }

  // combine the 4 quarter-wave partial sums
#pragma unroll
  for (int k = 0; k < 16; ++k) {
    a[k] += __shfl_xor(a[k], 16);
    a[k] += __shfl_xor(a[k], 32);
  }

  if (lane < 16) {
    float inv = 1.f / (float)(deg > 0 ? deg : 1);
    short8 r0, r1;
#pragma unroll
    for (int k = 0; k < 8; ++k) {
      r0[k] = (short)f2bf(a[k] * inv);
      r1[k] = (short)f2bf(a[8 + k] * inv);
    }
    *(short8*)&aggr[(size_t)node * D + fl * 16] = r0;
    *(short8*)&aggr[(size_t)node * D + fl * 16 + 8] = r1;
  }
}

// ---- f32 fallback aggr (aggr lives in d_out) ----------------------------
__global__ void aggr_f32_kernel(const float* __restrict__ xsrc, const int* __restrict__ offsets,
                                const int* __restrict__ edge_src, float* __restrict__ aggr) {
  int node = blockIdx.x;
  int t = threadIdx.x;
  int start = offsets[node], end = offsets[node + 1];
  float acc = 0.f;
  int i = start;
  for (; i + 4 <= end; i += 4) {
    int s0 = edge_src[i], s1 = edge_src[i + 1], s2 = edge_src[i + 2], s3 = edge_src[i + 3];
    acc += xsrc[(size_t)s0 * D + t];
    acc += xsrc[(size_t)s1 * D + t];
    acc += xsrc[(size_t)s2 * D + t];
    acc += xsrc[(size_t)s3 * D + t];
  }
  for (; i < end; ++i) acc += xsrc[(size_t)edge_src[i] * D + t];
  int deg = end - start;
  aggr[(size_t)node * D + t] = acc / (float)(deg > 0 ? deg : 1);
}

// ---- GEMM v3: 256x256 tile, K=512 in 8 chunks of 64, double-buffered ----
__global__ __launch_bounds__(512, 2) void gemm256_kernel(const unsigned short* __restrict__ aggr,
                                                         const float* __restrict__ xtgt,
                                                         const unsigned short* __restrict__ Wt,
                                                         const float* __restrict__ bias,
                                                         float* __restrict__ out, int n_tgt) {
  __shared__ __align__(16) unsigned short Abuf[2][16384];   // 32KB each
  __shared__ __align__(16) unsigned short Bbuf[2][16384];
  int t = threadIdx.x;
  int lane = t & 63, wid = t >> 6;
  int lr = lane & 15, lq = lane >> 4;
  int wr = wid >> 2, wc = wid & 3;
  int mbase = blockIdx.x * 256;

  floatx4 acc[8][4];
#pragma unroll
  for (int mt = 0; mt < 8; ++mt)
#pragma unroll
    for (int nt = 0; nt < 4; ++nt) acc[mt][nt] = (floatx4){0.f, 0.f, 0.f, 0.f};

  floatx4 st[8];   // reg-staging for x_tgt chunks

  auto stageA_gld = [&](int c, int buf) {
    int kbase = c * 64;
#pragma unroll
    for (int r = 0; r < 4; ++r) {
      int s = wid * 256 + r * 64 + lane;
      int row = s >> 3, ch = s & 7;
      int grow = mbase + row; if (grow >= n_tgt) grow = n_tgt - 1;
      const unsigned short* src = aggr + (size_t)grow * 256 + kbase + ((ch ^ (row & 7)) * 8);
      gld_lds16(src, &Abuf[buf][(size_t)(wid * 256 + r * 64) * 8]);
    }
  };
  auto stageB_gld = [&](int c, int buf) {
    int kbase = c * 64;
#pragma unroll
    for (int r = 0; r < 4; ++r) {
      int s = wid * 256 + r * 64 + lane;
      int oc = s >> 3, ch = s & 7;
      const unsigned short* src = Wt + (size_t)oc * 512 + kbase + ((ch ^ (oc & 7)) * 8);
      gld_lds16(src, &Bbuf[buf][(size_t)(wid * 256 + r * 64) * 8]);
    }
  };
  auto loadX = [&](int c) {
    int koff = c * 64 - 256;
#pragma unroll
    for (int r = 0; r < 4; ++r) {
      int s = r * 512 + t;
      int row = s >> 3, ch = s & 7;
      int grow = mbase + row; if (grow >= n_tgt) grow = n_tgt - 1;
      const float* src = xtgt + (size_t)grow * 256 + koff + ch * 8;
      st[2 * r]     = *(const floatx4*)src;
      st[2 * r + 1] = *(const floatx4*)(src + 4);
    }
  };
  auto writeX = [&](int buf) {
#pragma unroll
    for (int r = 0; r < 4; ++r) {
      int s = r * 512 + t;
      int row = s >> 3, ch = s & 7;
      short8 v;
      v[0] = (short)f2bf(st[2 * r][0]); v[1] = (short)f2bf(st[2 * r][1]);
      v[2] = (short)f2bf(st[2 * r][2]); v[3] = (short)f2bf(st[2 * r][3]);
      v[4] = (short)f2bf(st[2 * r + 1][0]); v[5] = (short)f2bf(st[2 * r + 1][1]);
      v[6] = (short)f2bf(st[2 * r + 1][2]); v[7] = (short)f2bf(st[2 * r + 1][3]);
      *(short8*)&Abuf[buf][(size_t)(row * 8 + (ch ^ (row & 7))) * 8] = v;
    }
  };
  auto compute = [&](int buf) {
#pragma unroll
    for (int ks2 = 0; ks2 < 2; ++ks2) {
      short8 b[4];
#pragma unroll
      for (int nt = 0; nt < 4; ++nt) {
        int oc = wc * 64 + nt * 16 + lr;
        int phys = (ks2 * 4 + lq) ^ (oc & 7);
        b[nt] = *(const short8*)&Bbuf[buf][(size_t)(oc * 8 + phys) * 8];
      }
#pragma unroll
      for (int mt = 0; mt < 8; ++mt) {
        int row = wr * 128 + mt * 16 + lr;
        int phys = (ks2 * 4 + lq) ^ (row & 7);
        short8 a = *(const short8*)&Abuf[buf][(size_t)(row * 8 + phys) * 8];
#pragma unroll
        for (int nt = 0; nt < 4; ++nt)
          acc[mt][nt] = __builtin_amdgcn_mfma_f32_16x16x32_bf16(a, b[nt], acc[mt][nt], 0, 0, 0);
      }
    }
  };

  stageA_gld(0, 0);
  stageB_gld(0, 0);
  __syncthreads();

  int cur = 0;
#pragma unroll
  for (int c = 0; c < 8; ++c) {
    int nxt = cur ^ 1;
    if (c + 1 < 8) {
      stageB_gld(c + 1, nxt);
      if (c + 1 < 4) stageA_gld(c + 1, nxt);
      else loadX(c + 1);
    }
    compute(cur);
    if (c + 1 >= 4 && c + 1 < 8) writeX(nxt);
    __syncthreads();
    cur = nxt;
  }

#pragma unroll
  for (int nt = 0; nt < 4; ++nt) {
    int oc = wc * 64 + nt * 16 + lr;
    float bv = bias[oc];
#pragma unroll
    for (int mt = 0; mt < 8; ++mt) {
#pragma unroll
      for (int r4 = 0; r4 < 4; ++r4) {
        int node = mbase + wr * 128 + mt * 16 + lq * 4 + r4;
        if (node < n_tgt) out[(size_t)node * D + oc] = acc[mt][nt][r4] + bv;
      }
    }
  }
}

// ---- fallback fused GEMM (f32 aggr in d_out), 64-row tile ---------------
__global__ __launch_bounds__(256) void gemm_fb_kernel(const float* __restrict__ aggrp,
                                                      const float* __restrict__ xtgt,
                                                      const unsigned short* __restrict__ Wt,
                                                      const float* __restrict__ bias,
                                                      float* __restrict__ out, int n_tgt) {
  __shared__ __align__(16) unsigned short A_lds[64 * 256];
  int t = threadIdx.x;
  int mbase = blockIdx.x * 64;
  int lane = t & 63, w = t >> 6;
  int lr = lane & 15, lq = lane >> 4;

  floatx4 acc[4][4];
#pragma unroll
  for (int mt = 0; mt < 4; ++mt)
#pragma unroll
    for (int nt = 0; nt < 4; ++nt) acc[mt][nt] = (floatx4){0.f, 0.f, 0.f, 0.f};

  const unsigned short* WtW = Wt + ((size_t)(64 * w + lr)) * 512 + lq * 8;

  for (int ph = 0; ph < 2; ++ph) {
    const float* srcbase = ph == 0 ? aggrp : xtgt;
#pragma unroll
    for (int it = 0; it < 8; ++it) {
      int chunk = it * 256 + t;
      int r = chunk >> 5, c = chunk & 31;
      int node = mbase + r;
      floatx4 f0 = {0.f, 0.f, 0.f, 0.f}, f1 = {0.f, 0.f, 0.f, 0.f};
      if (node < n_tgt) {
        f0 = *(const floatx4*)&srcbase[(size_t)node * D + c * 8];
        f1 = *(const floatx4*)&srcbase[(size_t)node * D + c * 8 + 4];
      }
      short8 v;
      v[0] = (short)f2bf(f0[0]); v[1] = (short)f2bf(f0[1]);
      v[2] = (short)f2bf(f0[2]); v[3] = (short)f2bf(f0[3]);
      v[4] = (short)f2bf(f1[0]); v[5] = (short)f2bf(f1[1]);
      v[6] = (short)f2bf(f1[2]); v[7] = (short)f2bf(f1[3]);
      int sc = c ^ (r & 7);
      *(short8*)&A_lds[r * 256 + sc * 8] = v;
    }
    __syncthreads();
#pragma unroll
    for (int ks = 0; ks < 8; ++ks) {
      short8 a[4], b[4];
#pragma unroll
      for (int mt = 0; mt < 4; ++mt) {
        int row = 16 * mt + lr;
        int chunk = (ks * 4 + lq) ^ (row & 7);
        a[mt] = *(const short8*)&A_lds[row * 256 + chunk * 8];
      }
#pragma unroll
      for (int nt = 0; nt < 4; ++nt)
        b[nt] = *(const short8*)&WtW[(size_t)nt * 16 * 512 + (ph * 8 + ks) * 32];
#pragma unroll
      for (int mt = 0; mt < 4; ++mt)
#pragma unroll
        for (int nt = 0; nt < 4; ++nt)
          acc[mt][nt] = __builtin_amdgcn_mfma_f32_16x16x32_bf16(a[mt], b[nt], acc[mt][nt], 0, 0, 0);
    }
    __syncthreads();
  }

#pragma unroll
  for (int nt = 0; nt < 4; ++nt) {
    int oc = 64 * w + 16 * nt + lr;
    float bv = bias[oc];
#pragma unroll
    for (int mt = 0; mt < 4; ++mt) {
#pragma unroll
      for (int r4 = 0; r4 < 4; ++r4) {
        int node = mbase + 16 * mt + lq * 4 + r4;
        if (node < n_tgt) out[(size_t)node * D + oc] = acc[mt][nt][r4] + bv;
      }
    }
  }
}

extern "C" void kernel_launch(void* const* d_in, const int* in_sizes, int n_in,
                              void* d_out, int out_size, void* d_ws, size_t ws_size,
                              hipStream_t stream) {
  const float* x_src = (const float*)d_in[0];
  const float* x_tgt = (const float*)d_in[1];
  const void* ei = d_in[2];
  const float* W_l = (const float*)d_in[3];
  const float* b_l = (const float*)d_in[4];
  const float* W_r = (const float*)d_in[5];
  float* out = (float*)d_out;

  const int N_s = in_sizes[0] / D;     // source nodes
  const int N_t = in_sizes[1] / D;     // target nodes
  const int E = in_sizes[2] / 2;       // edges

  char* ws = (char*)d_ws;
  size_t o = 0;
  auto alloc = [&](size_t bytes) { size_t cur = o; o = (o + bytes + 255) & ~(size_t)255; return cur; };
  int* flag              = (int*)(ws + alloc(4));
  int* counts            = (int*)(ws + alloc((size_t)N_t * 4));
  int* offsets           = (int*)(ws + alloc(((size_t)N_t + 1) * 4));
  int* cursor            = (int*)(ws + alloc((size_t)N_t * 4));
  size_t zero_end        = o;
  int SB = (N_t + 1023) / 1024;
  int* bsum              = (int*)(ws + alloc(((size_t)SB) * 4));
  int* boff              = (int*)(ws + alloc(((size_t)SB + 1) * 4));
  int* edge_src          = (int*)(ws + alloc((size_t)E * 4));
  unsigned short* Wt     = (unsigned short*)(ws + alloc((size_t)256 * 512 * 2));
  unsigned int* xf8      = (unsigned int*)(ws + alloc((size_t)N_s * D));       // fp8 table
  unsigned short* aggr_b = (unsigned short*)(ws + alloc((size_t)N_t * D * 2)); // bf16 aggr
  size_t f8_end          = o;

  bool f8_path = (ws_size >= f8_end);

  hipMemsetAsync(ws, 0, zero_end, stream);

  int eb = (E + 255) / 256;
  detect_kernel<<<1, 64, 0, stream>>>((const int*)ei, flag);
  count_kernel<<<eb, 256, 0, stream>>>(ei, flag, counts, E, N_t);
  scan_blocksum_kernel<<<SB, 256, 0, stream>>>(counts, bsum, N_t);
  scan_kernel<<<1, 1024, 0, stream>>>(bsum, boff, SB);
  scan_apply_kernel<<<SB, 256, 0, stream>>>(counts, boff, offsets, N_t);
  fill_kernel<<<eb, 256, 0, stream>>>(ei, flag, offsets, cursor, edge_src, E, N_t);
  wt_kernel<<<512, 256, 0, stream>>>(W_l, W_r, Wt);

  if (f8_path) {
    long long n16 = (long long)N_s * D / 16;
    xcast_f8_kernel<<<(int)((n16 + 255) / 256), 256, 0, stream>>>(x_src, xf8, n16);
    aggr_f8_kernel<<<(N_t + 3) / 4, 256, 0, stream>>>(xf8, offsets, edge_src, aggr_b, N_t);
    gemm256_kernel<<<(N_t + 255) / 256, 512, 0, stream>>>(aggr_b, x_tgt, Wt, b_l, out, N_t);
  } else {
    aggr_f32_kernel<<<N_t, 256, 0, stream>>>(x_src, offsets, edge_src, out);
    gemm_fb_kernel<<<(N_t + 63) / 64, 256, 0, stream>>>(out, x_tgt, Wt, b_l, out, N_t);
  }
}